// Round 9
// baseline (21470.151 us; speedup 1.0000x reference)
//
#include <hip/hip_runtime.h>
#include <hip/hip_bf16.h>

#define T_STEPS 4096
#define BATCH 8
#define DIN 512
#define NH 512
#define G4 2048
#define NWV 32
#define JPW 16

typedef __attribute__((ext_vector_type(8))) short bf16x8;
typedef __attribute__((ext_vector_type(4))) float f32x4;
typedef __attribute__((ext_vector_type(4))) int i32x4;

__device__ __forceinline__ unsigned short f2b(float f) {
  __hip_bfloat16 h = __float2bfloat16(f);
  return __builtin_bit_cast(unsigned short, h);
}
__device__ __forceinline__ float b2f(unsigned short u) {
  unsigned int x = ((unsigned int)u) << 16;
  return __builtin_bit_cast(float, x);
}
__device__ __forceinline__ float sigf(float x) { return 1.f / (1.f + __expf(-x)); }
__device__ __forceinline__ float tanh_fast(float x) { return 1.f - 2.f / (1.f + __expf(2.f * x)); }

// mailbox: u64 slot[parity][b(8)][jp(256)] = (tag<<32)|(bf16 h[2jp+1])<<16|(bf16 h[2jp])
__global__ __launch_bounds__(512) void init_ws(const float* __restrict__ h0,
                                               unsigned long long* __restrict__ mbox) {
  int tid = threadIdx.x;
  for (int i = tid; i < 2048; i += 512) {
    int b = i >> 8, m = i & 255;
    unsigned int pk = ((unsigned int)f2b(h0[b * NH + 2 * m + 1]) << 16) |
                      f2b(h0[b * NH + 2 * m]);
    mbox[i] = (unsigned long long)pk;         // parity 0: tag 0 + h0 data
    mbox[2048 + i] = 0xFFFFFFFFull << 32;     // parity 1: poison tag
  }
}

// ---------------- XI = x @ Wi + (bi + bh), swizzled to [t][wv][lane(32)][g*4+q] u16
#define BM 64
#define BN 64
#define BK 16
__global__ __launch_bounds__(256) void xi_gemm(const float* __restrict__ x,
                                               const float* __restrict__ Wi,
                                               const float* __restrict__ bi,
                                               const float* __restrict__ bh,
                                               unsigned short* __restrict__ xi) {
  __shared__ float As[BK][BM + 4];
  __shared__ float Bs[BK][BN + 4];
  const int tid = threadIdx.x;
  const int m0 = blockIdx.x * BM;
  const int n0 = blockIdx.y * BN;
  const int tx = tid & 15, ty = tid >> 4;
  const int arow = tid & 63, ak = (tid >> 6) << 2;
  const int bk = tid >> 4, bn = (tid & 15) << 2;
  float acc[4][4] = {};
  for (int k0 = 0; k0 < DIN; k0 += BK) {
    float4 av = *(const float4*)(x + (size_t)(m0 + arow) * DIN + k0 + ak);
    float4 bv = *(const float4*)(Wi + (size_t)(k0 + bk) * G4 + n0 + bn);
    __syncthreads();
    As[ak + 0][arow] = av.x;
    As[ak + 1][arow] = av.y;
    As[ak + 2][arow] = av.z;
    As[ak + 3][arow] = av.w;
    *(float4*)&Bs[bk][bn] = bv;
    __syncthreads();
#pragma unroll
    for (int kk = 0; kk < BK; ++kk) {
      float am[4], bw[4];
      *(float4*)am = *(const float4*)&As[kk][ty << 2];
      *(float4*)bw = *(const float4*)&Bs[kk][tx << 2];
#pragma unroll
      for (int i = 0; i < 4; ++i)
#pragma unroll
        for (int j = 0; j < 4; ++j) acc[i][j] = fmaf(am[i], bw[j], acc[i][j]);
    }
  }
  const int m_base = m0 + (ty << 2);
  const int n_base = n0 + (tx << 2);
  const int tt = m_base >> 3;
  const int rg = (m_base & 7) >> 2;
  const int gate = n_base >> 9;
  const int wv = (n_base & 511) >> 4;
  const int col0 = n_base & 15;
#pragma unroll
  for (int j = 0; j < 4; ++j) {
    int n = n_base + j;
    float bs = bi[n] + bh[n];
    unsigned long long pk = 0;
#pragma unroll
    for (int i = 0; i < 4; ++i)
      pk |= (unsigned long long)f2b(acc[i][j] + bs) << (16 * i);
    int lane = rg * 16 + col0 + j;
    size_t u16idx = (((size_t)tt * NWV + wv) * 32 + lane) * 16 + gate * 4;
    *(unsigned long long*)(xi + u16idx) = pk;
  }
}

// ---------------- persistent recurrence: 32 blocks x 64 threads (1 wave each).
// Tag-in-slot mailbox, all-sc0sc1: poll (= data read, 1 RT) -> compute ->
// publish dwordx4 {d,tag,d,tag} -> vmcnt(0) drain (R4-proven completion).
// out[] via LDS ring buffer (flush /16 steps); XI prefetch post-poll.
__global__ __launch_bounds__(64, 1) void lstm_rec(const float* __restrict__ Wh,
                                                  const float* __restrict__ h0c0,
                                                  const unsigned short* __restrict__ xi,
                                                  float* __restrict__ out,
                                                  unsigned long long* mbox) {
  const int wv = blockIdx.x;
  const int j0 = wv * JPW;
  const int lane = threadIdx.x;
  const int col = lane & 15;      // C col
  const int rg = lane >> 4;       // C row-group / A k-subblock (kq)

  __shared__ bf16x8 bwS[4][16][64];       // 64 KiB frag-layout Wh slice
  __shared__ float obuf[16][8][16];       // 8 KiB out ring buffer [st][b][jl]

  // ---- prologue: Wh slice -> LDS in frag layout
  {
    const int gp = lane >> 4, cp = lane & 15;
    const float* wsrc = Wh + (size_t)gp * NH + j0 + cp;
#pragma unroll 4
    for (int k = 0; k < 512; ++k) {
      float wval = wsrc[(size_t)k * G4];
      const int ks = k >> 5, kq = (k >> 3) & 3, e = k & 7;
      ((unsigned short*)&bwS[gp][ks][kq * 16 + cp])[e] = f2b(wval);
    }
  }
  __syncthreads();

  bf16x8 bwR0[16], bwR1[16];
#pragma unroll
  for (int ks = 0; ks < 16; ++ks) {
    bwR0[ks] = bwS[0][ks][lane];
    bwR1[ks] = bwS[1][ks][lane];
  }

  f32x4 cell = {0.f, 0.f, 0.f, 0.f};
  if (lane < 32) {
#pragma unroll
    for (int q = 0; q < 4; ++q)
      cell[q] = h0c0[(size_t)(BATCH + rg * 4 + q) * NH + j0 + col];
  }

  // ---- XI(0) preload
  i32x4 xiC0, xiC1, xiN0, xiN1;
  {
    const unsigned short* xp = xi + ((size_t)wv * 32 + (lane & 31)) * 16;
    asm volatile("global_load_dwordx4 %0, %1, off" : "=&v"(xiC0) : "v"(xp));
    asm volatile("global_load_dwordx4 %0, %1, off offset:16" : "=&v"(xiC1) : "v"(xp));
  }
  f32x4 hq = {0.f, 0.f, 0.f, 0.f};

  // consumer: batch cb = col&7, k-quarter kq = rg; reads slots [cb][kq*4 + ks*16 + 0..3]
  const char* mbase = (const char*)mbox + (size_t)(col & 7) * 2048 + (size_t)rg * 32;
  // producer: lanes 0..31: batch pb = lane>>2, unit pu = lane&3 (4 cols = 2 slots = 16B)
  const int pb = lane >> 2, pu = lane & 3;
  const int srcbase = ((pb >> 2) << 4) + (pu << 2);
  const int qs = pb & 3;
  char* pbase = (char*)mbox + (size_t)pb * 2048 + (size_t)j0 * 4 + (size_t)pu * 16;

  i32x4 aL[16], aH[16];

  for (int t = 0; t < T_STEPS; ++t) {
    const unsigned int tgt = (unsigned int)t;
    const char* mb = mbase + ((t & 1) << 14);

    // ---- (1) poll: 32 dwordx4 sc0sc1 burst = data+tags in ONE RT (R4-proven load form)
#define PL(i, o0, o1)                                                              \
    asm volatile("global_load_dwordx4 %0, %1, off offset:" #o0 " sc0 sc1"          \
                 : "=&v"(aL[i]) : "v"(mb));                                        \
    asm volatile("global_load_dwordx4 %0, %1, off offset:" #o1 " sc0 sc1"          \
                 : "=&v"(aH[i]) : "v"(mb));
#define ISSUE_ALL                                                                  \
    PL(0, 0, 16)       PL(1, 128, 144)    PL(2, 256, 272)    PL(3, 384, 400)       \
    PL(4, 512, 528)    PL(5, 640, 656)    PL(6, 768, 784)    PL(7, 896, 912)       \
    PL(8, 1024, 1040)  PL(9, 1152, 1168)  PL(10, 1280, 1296) PL(11, 1408, 1424)    \
    PL(12, 1536, 1552) PL(13, 1664, 1680) PL(14, 1792, 1808) PL(15, 1920, 1936)
    {
      unsigned int bad;
      int rounds = 0;
      for (;;) {
        ISSUE_ALL
        asm volatile("s_waitcnt vmcnt(0)" ::: "memory");
        __builtin_amdgcn_sched_barrier(0);
        bad = 0u;
#pragma unroll
        for (int ks = 0; ks < 16; ++ks) {
          bad |= ((unsigned int)aL[ks][1] ^ tgt) | ((unsigned int)aL[ks][3] ^ tgt) |
                 ((unsigned int)aH[ks][1] ^ tgt) | ((unsigned int)aH[ks][3] ^ tgt);
        }
        if (__all(bad == 0u)) break;
        if (++rounds > 4096) break;            // watchdog: wrong-fast, never hang
        if (rounds > 8) asm volatile("s_sleep 1");
      }
    }
#undef PL
#undef ISSUE_ALL

    // ---- (2) XI(t+1) prefetch (completes under compute; drained by publish drain)
    {
      const int tn = (t + 1 < T_STEPS) ? (t + 1) : t;
      const unsigned short* xp = xi + (((size_t)tn * NWV + wv) * 32 + (lane & 31)) * 16;
      asm volatile("global_load_dwordx4 %0, %1, off" : "=&v"(xiN0) : "v"(xp));
      asm volatile("global_load_dwordx4 %0, %1, off offset:16" : "=&v"(xiN1) : "v"(xp));
    }

    // ---- (3) acc seed from XI + 64 MFMAs
    f32x4 acc[4][2];
    {
      unsigned int wrd[8] = {(unsigned int)xiC0[0], (unsigned int)xiC0[1],
                             (unsigned int)xiC0[2], (unsigned int)xiC0[3],
                             (unsigned int)xiC1[0], (unsigned int)xiC1[1],
                             (unsigned int)xiC1[2], (unsigned int)xiC1[3]};
      f32x4 z = {0.f, 0.f, 0.f, 0.f};
#pragma unroll
      for (int g = 0; g < 4; ++g) {
#pragma unroll
        for (int q = 0; q < 4; ++q) {
          const int idx = g * 4 + q;
          acc[g][0][q] = b2f((unsigned short)(wrd[idx >> 1] >> ((idx & 1) * 16)));
        }
        acc[g][1] = z;
      }
    }
#pragma unroll
    for (int ks = 0; ks < 16; ++ks) {
      i32x4 fr = {aL[ks][0], aL[ks][2], aH[ks][0], aH[ks][2]};
      bf16x8 a = __builtin_bit_cast(bf16x8, fr);
      acc[0][ks & 1] = __builtin_amdgcn_mfma_f32_16x16x32_bf16(a, bwR0[ks], acc[0][ks & 1], 0, 0, 0);
      acc[1][ks & 1] = __builtin_amdgcn_mfma_f32_16x16x32_bf16(a, bwR1[ks], acc[1][ks & 1], 0, 0, 0);
      acc[2][ks & 1] = __builtin_amdgcn_mfma_f32_16x16x32_bf16(a, bwS[2][ks][lane], acc[2][ks & 1], 0, 0, 0);
      acc[3][ks & 1] = __builtin_amdgcn_mfma_f32_16x16x32_bf16(a, bwS[3][ks][lane], acc[3][ks & 1], 0, 0, 0);
    }

    // ---- (4) gates
#pragma unroll
    for (int q = 0; q < 4; ++q) {
      float pf = acc[0][0][q] + acc[0][1][q];
      float pi = acc[1][0][q] + acc[1][1][q];
      float po = acc[2][0][q] + acc[2][1][q];
      float pg = acc[3][0][q] + acc[3][1][q];
      float fg = sigf(pf), ig = sigf(pi), og = sigf(po), gg = tanh_fast(pg);
      float cn = fg * cell[q] + ig * gg;
      cell[q] = cn;
      hq[q] = og * tanh_fast(cn);
    }

    // ---- (5) publish h(t+1): shuffle-gather -> ONE dwordx4 {d,tag,d,tag} per lane<32,
    //      then vmcnt(0) drain (R4-proven store-completion pattern)
    {
      float v0 = 0.f, v1 = 0.f, v2 = 0.f, v3 = 0.f;
#pragma unroll
      for (int qq = 0; qq < 4; ++qq) {
        float s0 = __shfl(hq[qq], srcbase + 0);
        float s1 = __shfl(hq[qq], srcbase + 1);
        float s2 = __shfl(hq[qq], srcbase + 2);
        float s3 = __shfl(hq[qq], srcbase + 3);
        if (qq == qs) { v0 = s0; v1 = s1; v2 = s2; v3 = s3; }
      }
      if (lane < 32) {
        unsigned int tag1 = (unsigned int)(t + 1);
        i32x4 pub;
        pub[0] = (int)(((unsigned int)f2b(v1) << 16) | f2b(v0));
        pub[1] = (int)tag1;
        pub[2] = (int)(((unsigned int)f2b(v3) << 16) | f2b(v2));
        pub[3] = (int)tag1;
        char* pp = pbase + (((t + 1) & 1) << 14);
        asm volatile("global_store_dwordx4 %0, %1, off sc0 sc1" :: "v"(pp), "v"(pub) : "memory");
      }
    }
    asm volatile("s_waitcnt vmcnt(0)" ::: "memory");

    // ---- (6) out -> LDS ring buffer; bulk flush every 16 steps (post-drain,
    //      acks overlap next poll 1/16 of the time)
    if (lane < 32) {
      const int st = t & 15;
#pragma unroll
      for (int q = 0; q < 4; ++q) obuf[st][rg * 4 + q][col] = hq[q];
    }
    if ((t & 15) == 15) {
      const int t0 = t - 15;
#pragma unroll
      for (int it = 0; it < 8; ++it) {
        const int run = (lane >> 2) + it * 16;
        const int st = run >> 3, b = run & 7, jj = (lane & 3) << 2;
        float4 v = *(const float4*)&obuf[st][b][jj];
        *(float4*)(out + ((size_t)(t0 + st) * BATCH + b) * NH + j0 + jj) = v;
      }
    }
    xiC0 = xiN0;
    xiC1 = xiN1;
  }

  // ---- final state tail: [h_T ; c_T]
  if (lane < 32) {
    const size_t tail = (size_t)T_STEPS * BATCH * NH;
#pragma unroll
    for (int q = 0; q < 4; ++q) {
      out[tail + (size_t)(rg * 4 + q) * NH + j0 + col] = hq[q];
      out[tail + (size_t)BATCH * NH + (size_t)(rg * 4 + q) * NH + j0 + col] = cell[q];
    }
  }
}

extern "C" void kernel_launch(void* const* d_in, const int* in_sizes, int n_in,
                              void* d_out, int out_size, void* d_ws, size_t ws_size,
                              hipStream_t stream) {
  const float* x  = (const float*)d_in[0];
  const float* h0 = (const float*)d_in[1];
  const float* Wi = (const float*)d_in[2];
  const float* bi = (const float*)d_in[3];
  const float* Wh = (const float*)d_in[4];
  const float* bh = (const float*)d_in[5];
  float* out = (float*)d_out;

  // ws: [0, 32KB) mailbox u64[2][2048] | [64KB, +64MB) xi u16
  unsigned long long* mbox = (unsigned long long*)d_ws;
  unsigned short* xi = (unsigned short*)((char*)d_ws + 65536);

  init_ws<<<1, 512, 0, stream>>>(h0, mbox);
  dim3 g1((T_STEPS * BATCH) / BM, G4 / BN);
  xi_gemm<<<g1, 256, 0, stream>>>(x, Wi, bi, bh, xi);
  lstm_rec<<<NWV, 64, 0, stream>>>(Wh, h0, xi, out, mbox);
}

// Round 10
// 15114.909 us; speedup vs baseline: 1.4205x; 1.4205x over previous
//
#include <hip/hip_runtime.h>
#include <hip/hip_bf16.h>

#define T_STEPS 4096
#define BATCH 8
#define DIN 512
#define NH 512
#define G4 2048
#define NWV 32
#define JPW 16

typedef __attribute__((ext_vector_type(8))) short bf16x8;
typedef __attribute__((ext_vector_type(4))) float f32x4;
typedef __attribute__((ext_vector_type(4))) int i32x4;

__device__ __forceinline__ unsigned short f2b(float f) {
  __hip_bfloat16 h = __float2bfloat16(f);
  return __builtin_bit_cast(unsigned short, h);
}
__device__ __forceinline__ float b2f(unsigned short u) {
  unsigned int x = ((unsigned int)u) << 16;
  return __builtin_bit_cast(float, x);
}
__device__ __forceinline__ float sigf(float x) { return 1.f / (1.f + __expf(-x)); }
__device__ __forceinline__ float tanh_fast(float x) { return 1.f - 2.f / (1.f + __expf(2.f * x)); }

// ---------------- init: tags=0; hbuf parity0 = bf16(h0), parity1 = 0
__global__ __launch_bounds__(512) void init_ws(const float* __restrict__ h0,
                                               unsigned int* __restrict__ tags,
                                               unsigned short* __restrict__ hbuf) {
  int tid = threadIdx.x;
  if (tid < NWV) tags[tid] = 0u;
  for (int i = tid; i < 4096; i += 512) {   // [8 b][512 j] per parity
    int b = i >> 9, j = i & 511;
    hbuf[i] = f2b(h0[b * NH + j]);
    hbuf[4096 + i] = 0;
  }
}

// ---------------- XI = x @ Wi + (bi + bh), swizzled to [t][wv][lane(32)][g*4+q] u16
#define BM 64
#define BN 64
#define BK 16
__global__ __launch_bounds__(256) void xi_gemm(const float* __restrict__ x,
                                               const float* __restrict__ Wi,
                                               const float* __restrict__ bi,
                                               const float* __restrict__ bh,
                                               unsigned short* __restrict__ xi) {
  __shared__ float As[BK][BM + 4];
  __shared__ float Bs[BK][BN + 4];
  const int tid = threadIdx.x;
  const int m0 = blockIdx.x * BM;
  const int n0 = blockIdx.y * BN;
  const int tx = tid & 15, ty = tid >> 4;
  const int arow = tid & 63, ak = (tid >> 6) << 2;
  const int bk = tid >> 4, bn = (tid & 15) << 2;
  float acc[4][4] = {};
  for (int k0 = 0; k0 < DIN; k0 += BK) {
    float4 av = *(const float4*)(x + (size_t)(m0 + arow) * DIN + k0 + ak);
    float4 bv = *(const float4*)(Wi + (size_t)(k0 + bk) * G4 + n0 + bn);
    __syncthreads();
    As[ak + 0][arow] = av.x;
    As[ak + 1][arow] = av.y;
    As[ak + 2][arow] = av.z;
    As[ak + 3][arow] = av.w;
    *(float4*)&Bs[bk][bn] = bv;
    __syncthreads();
#pragma unroll
    for (int kk = 0; kk < BK; ++kk) {
      float am[4], bw[4];
      *(float4*)am = *(const float4*)&As[kk][ty << 2];
      *(float4*)bw = *(const float4*)&Bs[kk][tx << 2];
#pragma unroll
      for (int i = 0; i < 4; ++i)
#pragma unroll
        for (int j = 0; j < 4; ++j) acc[i][j] = fmaf(am[i], bw[j], acc[i][j]);
    }
  }
  const int m_base = m0 + (ty << 2);
  const int n_base = n0 + (tx << 2);
  const int tt = m_base >> 3;
  const int rg = (m_base & 7) >> 2;
  const int gate = n_base >> 9;
  const int wv = (n_base & 511) >> 4;
  const int col0 = n_base & 15;
#pragma unroll
  for (int j = 0; j < 4; ++j) {
    int n = n_base + j;
    float bs = bi[n] + bh[n];
    unsigned long long pk = 0;
#pragma unroll
    for (int i = 0; i < 4; ++i)
      pk |= (unsigned long long)f2b(acc[i][j] + bs) << (16 * i);
    int lane = rg * 16 + col0 + j;
    size_t u16idx = (((size_t)tt * NWV + wv) * 32 + lane) * 16 + gate * 4;
    *(unsigned long long*)(xi + u16idx) = pk;
  }
}

// ---------------- persistent recurrence: 32 blocks x 64 threads (1 wave each).
// R8 protocol EXACTLY, with one change: all mailbox/tag traffic at AGENT scope
// (sc1 = LLC coherence point) instead of SYSTEM scope (sc0 sc1 = HBM path).
// R2 proved agent-scope store->load visibility across XCDs; R8 proved the
// ordering/protocol. This cuts each sync RT from ~HBM to ~LLC latency.
__global__ __launch_bounds__(64, 1) void lstm_rec(const float* __restrict__ Wh,
                                                  const float* __restrict__ h0c0,
                                                  const unsigned short* __restrict__ xi,
                                                  float* __restrict__ out,
                                                  unsigned int* tags,
                                                  unsigned short* hbuf) {
  const int wv = blockIdx.x;
  const int j0 = wv * JPW;
  const int lane = threadIdx.x;
  const int col = lane & 15;      // C col / loader batch-row
  const int rg = lane >> 4;       // C row-group / A k-subblock

  __shared__ bf16x8 bwS[4][16][64];   // 64 KiB frag-layout Wh slice

  // ---- prologue: Wh slice -> LDS in frag layout
  {
    const int gp = lane >> 4, cp = lane & 15;
    const float* wsrc = Wh + (size_t)gp * NH + j0 + cp;
#pragma unroll 4
    for (int k = 0; k < 512; ++k) {
      float wval = wsrc[(size_t)k * G4];
      const int ks = k >> 5, kq = (k >> 3) & 3, e = k & 7;
      ((unsigned short*)&bwS[gp][ks][kq * 16 + cp])[e] = f2b(wval);
    }
  }
  __syncthreads();

  bf16x8 bwR0[16], bwR1[16];
#pragma unroll
  for (int ks = 0; ks < 16; ++ks) {
    bwR0[ks] = bwS[0][ks][lane];
    bwR1[ks] = bwS[1][ks][lane];
  }

  f32x4 cell = {0.f, 0.f, 0.f, 0.f};
  if (lane < 32) {
#pragma unroll
    for (int q = 0; q < 4; ++q)
      cell[q] = h0c0[(size_t)(BATCH + rg * 4 + q) * NH + j0 + col];
  }

  // ---- XI(0) preload
  i32x4 xiC0, xiC1, xiN0, xiN1;
  {
    const unsigned short* xp = xi + ((size_t)wv * 32 + (lane & 31)) * 16;
    asm volatile("global_load_dwordx4 %0, %1, off" : "=&v"(xiC0) : "v"(xp));
    asm volatile("global_load_dwordx4 %0, %1, off offset:16" : "=&v"(xiC1) : "v"(xp));
  }
  f32x4 hq = {0.f, 0.f, 0.f, 0.f};

  const unsigned int* tp = tags + (lane & 31);
  unsigned int* myTag = tags + wv;

  for (int t = 0; t < T_STEPS; ++t) {
    // ---- (1) poll: one agent-scope dword per lane per retry (also drains
    //      the previous step's post-tag out/XI traffic in parallel with tag wait)
    {
      unsigned int tv;
      do {
        asm volatile("global_load_dword %0, %1, off sc1\n\ts_waitcnt vmcnt(0)"
                     : "=v"(tv) : "v"(tp) : "memory");
      } while (__any((int)tv < t));
    }

    // ---- (2) h(t): 16 pipelined agent-scope dwordx4 loads (clamped, no divergence)
    const unsigned short* mb = hbuf + ((t & 1) << 12);
    const unsigned short* ap = mb + (col & 7) * 512 + (rg << 3);
    i32x4 afr[16];
    asm volatile("global_load_dwordx4 %0, %1, off sc1" : "=v"(afr[0]) : "v"(ap));
    asm volatile("global_load_dwordx4 %0, %1, off offset:64 sc1" : "=v"(afr[1]) : "v"(ap));
    asm volatile("global_load_dwordx4 %0, %1, off offset:128 sc1" : "=v"(afr[2]) : "v"(ap));
    asm volatile("global_load_dwordx4 %0, %1, off offset:192 sc1" : "=v"(afr[3]) : "v"(ap));
    asm volatile("global_load_dwordx4 %0, %1, off offset:256 sc1" : "=v"(afr[4]) : "v"(ap));
    asm volatile("global_load_dwordx4 %0, %1, off offset:320 sc1" : "=v"(afr[5]) : "v"(ap));
    asm volatile("global_load_dwordx4 %0, %1, off offset:384 sc1" : "=v"(afr[6]) : "v"(ap));
    asm volatile("global_load_dwordx4 %0, %1, off offset:448 sc1" : "=v"(afr[7]) : "v"(ap));
    asm volatile("global_load_dwordx4 %0, %1, off offset:512 sc1" : "=v"(afr[8]) : "v"(ap));
    asm volatile("global_load_dwordx4 %0, %1, off offset:576 sc1" : "=v"(afr[9]) : "v"(ap));
    asm volatile("global_load_dwordx4 %0, %1, off offset:640 sc1" : "=v"(afr[10]) : "v"(ap));
    asm volatile("global_load_dwordx4 %0, %1, off offset:704 sc1" : "=v"(afr[11]) : "v"(ap));
    asm volatile("global_load_dwordx4 %0, %1, off offset:768 sc1" : "=v"(afr[12]) : "v"(ap));
    asm volatile("global_load_dwordx4 %0, %1, off offset:832 sc1" : "=v"(afr[13]) : "v"(ap));
    asm volatile("global_load_dwordx4 %0, %1, off offset:896 sc1" : "=v"(afr[14]) : "v"(ap));
    asm volatile("global_load_dwordx4 %0, %1, off offset:960 sc1" : "=v"(afr[15]) : "v"(ap));
    // ---- (3) wait for h data; fence the scheduler (rule #18)
    asm volatile("s_waitcnt vmcnt(0)" ::: "memory");
    __builtin_amdgcn_sched_barrier(0);

    // ---- (4) acc seed from XI + 64 MFMAs
    f32x4 acc[4][2];
    {
      unsigned int wrd[8] = {(unsigned int)xiC0[0], (unsigned int)xiC0[1],
                             (unsigned int)xiC0[2], (unsigned int)xiC0[3],
                             (unsigned int)xiC1[0], (unsigned int)xiC1[1],
                             (unsigned int)xiC1[2], (unsigned int)xiC1[3]};
      f32x4 z = {0.f, 0.f, 0.f, 0.f};
#pragma unroll
      for (int g = 0; g < 4; ++g) {
#pragma unroll
        for (int q = 0; q < 4; ++q) {
          const int idx = g * 4 + q;
          acc[g][0][q] = b2f((unsigned short)(wrd[idx >> 1] >> ((idx & 1) * 16)));
        }
        acc[g][1] = z;
      }
    }
#pragma unroll
    for (int ks = 0; ks < 16; ++ks) {
      bf16x8 a = __builtin_bit_cast(bf16x8, afr[ks]);
      acc[0][ks & 1] = __builtin_amdgcn_mfma_f32_16x16x32_bf16(a, bwR0[ks], acc[0][ks & 1], 0, 0, 0);
      acc[1][ks & 1] = __builtin_amdgcn_mfma_f32_16x16x32_bf16(a, bwR1[ks], acc[1][ks & 1], 0, 0, 0);
      acc[2][ks & 1] = __builtin_amdgcn_mfma_f32_16x16x32_bf16(a, bwS[2][ks][lane], acc[2][ks & 1], 0, 0, 0);
      acc[3][ks & 1] = __builtin_amdgcn_mfma_f32_16x16x32_bf16(a, bwS[3][ks][lane], acc[3][ks & 1], 0, 0, 0);
    }

    // ---- (5) gates
#pragma unroll
    for (int q = 0; q < 4; ++q) {
      float pf = acc[0][0][q] + acc[0][1][q];
      float pi = acc[1][0][q] + acc[1][1][q];
      float po = acc[2][0][q] + acc[2][1][q];
      float pg = acc[3][0][q] + acc[3][1][q];
      float fg = sigf(pf), ig = sigf(pi), og = sigf(po), gg = tanh_fast(pg);
      float cn = fg * cell[q] + ig * gg;
      cell[q] = cn;
      hq[q] = og * tanh_fast(cn);
    }

    // ---- (6) publish h(t+1): 4 agent-scope u16 stores per lane (own values)
    if (lane < 32) {
      unsigned short* pp = hbuf + (((t + 1) & 1) << 12) + (rg * 4) * 512 + j0 + col;
      unsigned int h0u = f2b(hq[0]), h1u = f2b(hq[1]), h2u = f2b(hq[2]), h3u = f2b(hq[3]);
      asm volatile("global_store_short %0, %1, off sc1" :: "v"(pp), "v"(h0u) : "memory");
      asm volatile("global_store_short %0, %1, off offset:1024 sc1" :: "v"(pp), "v"(h1u) : "memory");
      asm volatile("global_store_short %0, %1, off offset:2048 sc1" :: "v"(pp), "v"(h2u) : "memory");
      asm volatile("global_store_short %0, %1, off offset:3072 sc1" :: "v"(pp), "v"(h3u) : "memory");
    }
    // ---- (7) drain publish (LLC acks only — nothing else outstanding)
    asm volatile("s_waitcnt vmcnt(0)" ::: "memory");
    // ---- (8) tag store (agent scope)
    if (lane == 0) {
      unsigned int tn1 = (unsigned int)(t + 1);
      asm volatile("global_store_dword %0, %1, off sc1" :: "v"(myTag), "v"(tn1) : "memory");
    }

    // ---- (9) POST-tag: out stores + XI(t+1) prefetch (acks/latency overlap next poll)
    if (lane < 32) {
#pragma unroll
      for (int q = 0; q < 4; ++q)
        out[((size_t)t * BATCH + (rg * 4 + q)) * NH + j0 + col] = hq[q];
    }
    {
      const int tn = (t + 1 < T_STEPS) ? (t + 1) : t;
      const unsigned short* xp = xi + (((size_t)tn * NWV + wv) * 32 + (lane & 31)) * 16;
      asm volatile("global_load_dwordx4 %0, %1, off" : "=&v"(xiN0) : "v"(xp));
      asm volatile("global_load_dwordx4 %0, %1, off offset:16" : "=&v"(xiN1) : "v"(xp));
    }
    xiC0 = xiN0;
    xiC1 = xiN1;
  }

  // ---- final state tail: [h_T ; c_T]
  if (lane < 32) {
    const size_t tail = (size_t)T_STEPS * BATCH * NH;
#pragma unroll
    for (int q = 0; q < 4; ++q) {
      out[tail + (size_t)(rg * 4 + q) * NH + j0 + col] = hq[q];
      out[tail + (size_t)BATCH * NH + (size_t)(rg * 4 + q) * NH + j0 + col] = cell[q];
    }
  }
}

extern "C" void kernel_launch(void* const* d_in, const int* in_sizes, int n_in,
                              void* d_out, int out_size, void* d_ws, size_t ws_size,
                              hipStream_t stream) {
  const float* x  = (const float*)d_in[0];
  const float* h0 = (const float*)d_in[1];
  const float* Wi = (const float*)d_in[2];
  const float* bi = (const float*)d_in[3];
  const float* Wh = (const float*)d_in[4];
  const float* bh = (const float*)d_in[5];
  float* out = (float*)d_out;

  unsigned int* tags = (unsigned int*)d_ws;
  unsigned short* hbuf = (unsigned short*)((char*)d_ws + 256);
  unsigned short* xi = (unsigned short*)((char*)d_ws + 65536);

  init_ws<<<1, 512, 0, stream>>>(h0, tags, hbuf);
  dim3 g1((T_STEPS * BATCH) / BM, G4 / BN);
  xi_gemm<<<g1, 256, 0, stream>>>(x, Wi, bi, bh, xi);
  lstm_rec<<<NWV, 64, 0, stream>>>(Wh, h0, xi, out, tags, hbuf);
}

// Round 13
// 13944.267 us; speedup vs baseline: 1.5397x; 1.0840x over previous
//
#include <hip/hip_runtime.h>
#include <hip/hip_bf16.h>

#define T_STEPS 4096
#define BATCH 8
#define DIN 512
#define NH 512
#define G4 2048
#define NWV 32
#define JPW 16

typedef __attribute__((ext_vector_type(8))) short bf16x8;
typedef __attribute__((ext_vector_type(4))) float f32x4;
typedef __attribute__((ext_vector_type(4))) int i32x4;

__device__ __forceinline__ unsigned short f2b(float f) {
  __hip_bfloat16 h = __float2bfloat16(f);
  return __builtin_bit_cast(unsigned short, h);
}
__device__ __forceinline__ float b2f(unsigned short u) {
  unsigned int x = ((unsigned int)u) << 16;
  return __builtin_bit_cast(float, x);
}
__device__ __forceinline__ float sigf(float x) { return 1.f / (1.f + __expf(-x)); }
__device__ __forceinline__ float tanh_fast(float x) { return 1.f - 2.f / (1.f + __expf(2.f * x)); }

// ---------------- init: tags=0; hbuf parity0 = bf16(h0), parity1 = 0
__global__ __launch_bounds__(512) void init_ws(const float* __restrict__ h0,
                                               unsigned int* __restrict__ tags,
                                               unsigned short* __restrict__ hbuf) {
  int tid = threadIdx.x;
  if (tid < NWV) tags[tid] = 0u;
  for (int i = tid; i < 4096; i += 512) {   // [8 b][512 j] per parity
    int b = i >> 9, j = i & 511;
    hbuf[i] = f2b(h0[b * NH + j]);
    hbuf[4096 + i] = 0;
  }
}

// ---------------- XI = x @ Wi + (bi + bh), swizzled to [t][wv][lane(32)][g*4+q] u16
#define BM 64
#define BN 64
#define BK 16
__global__ __launch_bounds__(256) void xi_gemm(const float* __restrict__ x,
                                               const float* __restrict__ Wi,
                                               const float* __restrict__ bi,
                                               const float* __restrict__ bh,
                                               unsigned short* __restrict__ xi) {
  __shared__ float As[BK][BM + 4];
  __shared__ float Bs[BK][BN + 4];
  const int tid = threadIdx.x;
  const int m0 = blockIdx.x * BM;
  const int n0 = blockIdx.y * BN;
  const int tx = tid & 15, ty = tid >> 4;
  const int arow = tid & 63, ak = (tid >> 6) << 2;
  const int bk = tid >> 4, bn = (tid & 15) << 2;
  float acc[4][4] = {};
  for (int k0 = 0; k0 < DIN; k0 += BK) {
    float4 av = *(const float4*)(x + (size_t)(m0 + arow) * DIN + k0 + ak);
    float4 bv = *(const float4*)(Wi + (size_t)(k0 + bk) * G4 + n0 + bn);
    __syncthreads();
    As[ak + 0][arow] = av.x;
    As[ak + 1][arow] = av.y;
    As[ak + 2][arow] = av.z;
    As[ak + 3][arow] = av.w;
    *(float4*)&Bs[bk][bn] = bv;
    __syncthreads();
#pragma unroll
    for (int kk = 0; kk < BK; ++kk) {
      float am[4], bw[4];
      *(float4*)am = *(const float4*)&As[kk][ty << 2];
      *(float4*)bw = *(const float4*)&Bs[kk][tx << 2];
#pragma unroll
      for (int i = 0; i < 4; ++i)
#pragma unroll
        for (int j = 0; j < 4; ++j) acc[i][j] = fmaf(am[i], bw[j], acc[i][j]);
    }
  }
  const int m_base = m0 + (ty << 2);
  const int n_base = n0 + (tx << 2);
  const int tt = m_base >> 3;
  const int rg = (m_base & 7) >> 2;
  const int gate = n_base >> 9;
  const int wv = (n_base & 511) >> 4;
  const int col0 = n_base & 15;
#pragma unroll
  for (int j = 0; j < 4; ++j) {
    int n = n_base + j;
    float bs = bi[n] + bh[n];
    unsigned long long pk = 0;
#pragma unroll
    for (int i = 0; i < 4; ++i)
      pk |= (unsigned long long)f2b(acc[i][j] + bs) << (16 * i);
    int lane = rg * 16 + col0 + j;
    size_t u16idx = (((size_t)tt * NWV + wv) * 32 + lane) * 16 + gate * 4;
    *(unsigned long long*)(xi + u16idx) = pk;
  }
}

// ---------------- persistent recurrence: 32 blocks x 64 threads (1 wave each).
// R10 protocol exactly (sc1 tag poll -> sc1 data burst -> compute -> sc1 publish
// -> vmcnt(0) -> sc1 tag store -> post-tag out/XI). Two latency micro-opts:
//   (1) pipelined 2-deep tag poll (check cadence RT/2)
//   (2) staged burst waits vmcnt(12/8/4/0), MFMA overlapped with burst tail
__global__ __launch_bounds__(64, 1) void lstm_rec(const float* __restrict__ Wh,
                                                  const float* __restrict__ h0c0,
                                                  const unsigned short* __restrict__ xi,
                                                  float* __restrict__ out,
                                                  unsigned int* tags,
                                                  unsigned short* hbuf) {
  const int wv = blockIdx.x;
  const int j0 = wv * JPW;
  const int lane = threadIdx.x;
  const int col = lane & 15;      // C col / loader batch-row
  const int rg = lane >> 4;       // C row-group / A k-subblock

  __shared__ bf16x8 bwS[4][16][64];   // 64 KiB frag-layout Wh slice

  // ---- prologue: Wh slice -> LDS in frag layout
  {
    const int gp = lane >> 4, cp = lane & 15;
    const float* wsrc = Wh + (size_t)gp * NH + j0 + cp;
#pragma unroll 4
    for (int k = 0; k < 512; ++k) {
      float wval = wsrc[(size_t)k * G4];
      const int ks = k >> 5, kq = (k >> 3) & 3, e = k & 7;
      ((unsigned short*)&bwS[gp][ks][kq * 16 + cp])[e] = f2b(wval);
    }
  }
  __syncthreads();

  bf16x8 bwR0[16], bwR1[16];
#pragma unroll
  for (int ks = 0; ks < 16; ++ks) {
    bwR0[ks] = bwS[0][ks][lane];
    bwR1[ks] = bwS[1][ks][lane];
  }

  f32x4 cell = {0.f, 0.f, 0.f, 0.f};
  if (lane < 32) {
#pragma unroll
    for (int q = 0; q < 4; ++q)
      cell[q] = h0c0[(size_t)(BATCH + rg * 4 + q) * NH + j0 + col];
  }

  // ---- XI(0) preload
  i32x4 xiC0, xiC1, xiN0, xiN1;
  {
    const unsigned short* xp = xi + ((size_t)wv * 32 + (lane & 31)) * 16;
    asm volatile("global_load_dwordx4 %0, %1, off" : "=&v"(xiC0) : "v"(xp));
    asm volatile("global_load_dwordx4 %0, %1, off offset:16" : "=&v"(xiC1) : "v"(xp));
  }
  f32x4 hq = {0.f, 0.f, 0.f, 0.f};

  const unsigned int* tp = tags + (lane & 31);
  unsigned int* myTag = tags + wv;

  for (int t = 0; t < T_STEPS; ++t) {
    // ---- (1) pipelined tag poll: 2 loads in flight, alternate vmcnt(1) checks.
    //      (First iterations also drain prior post-tag out/XI traffic — same as R10.)
    {
      unsigned int tvA, tvB;
      asm volatile("global_load_dword %0, %1, off sc1" : "=&v"(tvA) : "v"(tp) : "memory");
      for (;;) {
        asm volatile("global_load_dword %0, %1, off sc1" : "=&v"(tvB) : "v"(tp) : "memory");
        asm volatile("s_waitcnt vmcnt(1)" ::: "memory");   // tvA ready
        __builtin_amdgcn_sched_barrier(0);
        if (__all((int)tvA >= t)) break;
        asm volatile("global_load_dword %0, %1, off sc1" : "=&v"(tvA) : "v"(tp) : "memory");
        asm volatile("s_waitcnt vmcnt(1)" ::: "memory");   // tvB ready
        __builtin_amdgcn_sched_barrier(0);
        if (__all((int)tvB >= t)) break;
      }
      asm volatile("s_waitcnt vmcnt(0)" ::: "memory");     // retire leftover poll load
      __builtin_amdgcn_sched_barrier(0);
    }

    // ---- (2) acc seed from XI (VALU only; runs while nothing outstanding)
    f32x4 acc[4][2];
    {
      unsigned int wrd[8] = {(unsigned int)xiC0[0], (unsigned int)xiC0[1],
                             (unsigned int)xiC0[2], (unsigned int)xiC0[3],
                             (unsigned int)xiC1[0], (unsigned int)xiC1[1],
                             (unsigned int)xiC1[2], (unsigned int)xiC1[3]};
      f32x4 z = {0.f, 0.f, 0.f, 0.f};
#pragma unroll
      for (int g = 0; g < 4; ++g) {
#pragma unroll
        for (int q = 0; q < 4; ++q) {
          const int idx = g * 4 + q;
          acc[g][0][q] = b2f((unsigned short)(wrd[idx >> 1] >> ((idx & 1) * 16)));
        }
        acc[g][1] = z;
      }
    }

    // ---- (3) h(t) burst: 16 sc1 dwordx4 issued back-to-back (vmcnt clean here)
    const unsigned short* mb = hbuf + ((t & 1) << 12);
    const unsigned short* ap = mb + (col & 7) * 512 + (rg << 3);
    i32x4 afr[16];
    asm volatile("global_load_dwordx4 %0, %1, off sc1" : "=v"(afr[0]) : "v"(ap));
    asm volatile("global_load_dwordx4 %0, %1, off offset:64 sc1" : "=v"(afr[1]) : "v"(ap));
    asm volatile("global_load_dwordx4 %0, %1, off offset:128 sc1" : "=v"(afr[2]) : "v"(ap));
    asm volatile("global_load_dwordx4 %0, %1, off offset:192 sc1" : "=v"(afr[3]) : "v"(ap));
    asm volatile("global_load_dwordx4 %0, %1, off offset:256 sc1" : "=v"(afr[4]) : "v"(ap));
    asm volatile("global_load_dwordx4 %0, %1, off offset:320 sc1" : "=v"(afr[5]) : "v"(ap));
    asm volatile("global_load_dwordx4 %0, %1, off offset:384 sc1" : "=v"(afr[6]) : "v"(ap));
    asm volatile("global_load_dwordx4 %0, %1, off offset:448 sc1" : "=v"(afr[7]) : "v"(ap));
    asm volatile("global_load_dwordx4 %0, %1, off offset:512 sc1" : "=v"(afr[8]) : "v"(ap));
    asm volatile("global_load_dwordx4 %0, %1, off offset:576 sc1" : "=v"(afr[9]) : "v"(ap));
    asm volatile("global_load_dwordx4 %0, %1, off offset:640 sc1" : "=v"(afr[10]) : "v"(ap));
    asm volatile("global_load_dwordx4 %0, %1, off offset:704 sc1" : "=v"(afr[11]) : "v"(ap));
    asm volatile("global_load_dwordx4 %0, %1, off offset:768 sc1" : "=v"(afr[12]) : "v"(ap));
    asm volatile("global_load_dwordx4 %0, %1, off offset:832 sc1" : "=v"(afr[13]) : "v"(ap));
    asm volatile("global_load_dwordx4 %0, %1, off offset:896 sc1" : "=v"(afr[14]) : "v"(ap));
    asm volatile("global_load_dwordx4 %0, %1, off offset:960 sc1" : "=v"(afr[15]) : "v"(ap));

    // ---- (4) staged consume: vmcnt retires in issue order -> 4 groups of 4 loads,
    //      16 MFMAs each, overlapping compute with the burst tail (rule #18 fences)
#define MFMA4(ks)                                                                          \
    {                                                                                      \
      bf16x8 a = __builtin_bit_cast(bf16x8, afr[ks]);                                      \
      acc[0][(ks) & 1] = __builtin_amdgcn_mfma_f32_16x16x32_bf16(a, bwR0[ks], acc[0][(ks) & 1], 0, 0, 0); \
      acc[1][(ks) & 1] = __builtin_amdgcn_mfma_f32_16x16x32_bf16(a, bwR1[ks], acc[1][(ks) & 1], 0, 0, 0); \
      acc[2][(ks) & 1] = __builtin_amdgcn_mfma_f32_16x16x32_bf16(a, bwS[2][ks][lane], acc[2][(ks) & 1], 0, 0, 0); \
      acc[3][(ks) & 1] = __builtin_amdgcn_mfma_f32_16x16x32_bf16(a, bwS[3][ks][lane], acc[3][(ks) & 1], 0, 0, 0); \
    }
    asm volatile("s_waitcnt vmcnt(12)" ::: "memory");
    __builtin_amdgcn_sched_barrier(0);
    MFMA4(0) MFMA4(1) MFMA4(2) MFMA4(3)
    asm volatile("s_waitcnt vmcnt(8)" ::: "memory");
    __builtin_amdgcn_sched_barrier(0);
    MFMA4(4) MFMA4(5) MFMA4(6) MFMA4(7)
    asm volatile("s_waitcnt vmcnt(4)" ::: "memory");
    __builtin_amdgcn_sched_barrier(0);
    MFMA4(8) MFMA4(9) MFMA4(10) MFMA4(11)
    asm volatile("s_waitcnt vmcnt(0)" ::: "memory");
    __builtin_amdgcn_sched_barrier(0);
    MFMA4(12) MFMA4(13) MFMA4(14) MFMA4(15)
#undef MFMA4

    // ---- (5) gates
#pragma unroll
    for (int q = 0; q < 4; ++q) {
      float pf = acc[0][0][q] + acc[0][1][q];
      float pi = acc[1][0][q] + acc[1][1][q];
      float po = acc[2][0][q] + acc[2][1][q];
      float pg = acc[3][0][q] + acc[3][1][q];
      float fg = sigf(pf), ig = sigf(pi), og = sigf(po), gg = tanh_fast(pg);
      float cn = fg * cell[q] + ig * gg;
      cell[q] = cn;
      hq[q] = og * tanh_fast(cn);
    }

    // ---- (6) publish h(t+1): 4 sc1 u16 stores per lane (own values, R10-proven)
    if (lane < 32) {
      unsigned short* pp = hbuf + (((t + 1) & 1) << 12) + (rg * 4) * 512 + j0 + col;
      unsigned int h0u = f2b(hq[0]), h1u = f2b(hq[1]), h2u = f2b(hq[2]), h3u = f2b(hq[3]);
      asm volatile("global_store_short %0, %1, off sc1" :: "v"(pp), "v"(h0u) : "memory");
      asm volatile("global_store_short %0, %1, off offset:1024 sc1" :: "v"(pp), "v"(h1u) : "memory");
      asm volatile("global_store_short %0, %1, off offset:2048 sc1" :: "v"(pp), "v"(h2u) : "memory");
      asm volatile("global_store_short %0, %1, off offset:3072 sc1" :: "v"(pp), "v"(h3u) : "memory");
    }
    // ---- (7) drain publish (nothing else outstanding)
    asm volatile("s_waitcnt vmcnt(0)" ::: "memory");
    // ---- (8) tag store
    if (lane == 0) {
      unsigned int tn1 = (unsigned int)(t + 1);
      asm volatile("global_store_dword %0, %1, off sc1" :: "v"(myTag), "v"(tn1) : "memory");
    }

    // ---- (9) POST-tag: out stores + XI(t+1) prefetch (acks overlap next poll)
    if (lane < 32) {
#pragma unroll
      for (int q = 0; q < 4; ++q)
        out[((size_t)t * BATCH + (rg * 4 + q)) * NH + j0 + col] = hq[q];
    }
    {
      const int tn = (t + 1 < T_STEPS) ? (t + 1) : t;
      const unsigned short* xp = xi + (((size_t)tn * NWV + wv) * 32 + (lane & 31)) * 16;
      asm volatile("global_load_dwordx4 %0, %1, off" : "=&v"(xiN0) : "v"(xp));
      asm volatile("global_load_dwordx4 %0, %1, off offset:16" : "=&v"(xiN1) : "v"(xp));
    }
    xiC0 = xiN0;
    xiC1 = xiN1;
  }

  // ---- final state tail: [h_T ; c_T]
  if (lane < 32) {
    const size_t tail = (size_t)T_STEPS * BATCH * NH;
#pragma unroll
    for (int q = 0; q < 4; ++q) {
      out[tail + (size_t)(rg * 4 + q) * NH + j0 + col] = hq[q];
      out[tail + (size_t)BATCH * NH + (size_t)(rg * 4 + q) * NH + j0 + col] = cell[q];
    }
  }
}

extern "C" void kernel_launch(void* const* d_in, const int* in_sizes, int n_in,
                              void* d_out, int out_size, void* d_ws, size_t ws_size,
                              hipStream_t stream) {
  const float* x  = (const float*)d_in[0];
  const float* h0 = (const float*)d_in[1];
  const float* Wi = (const float*)d_in[2];
  const float* bi = (const float*)d_in[3];
  const float* Wh = (const float*)d_in[4];
  const float* bh = (const float*)d_in[5];
  float* out = (float*)d_out;

  unsigned int* tags = (unsigned int*)d_ws;
  unsigned short* hbuf = (unsigned short*)((char*)d_ws + 256);
  unsigned short* xi = (unsigned short*)((char*)d_ws + 65536);

  init_ws<<<1, 512, 0, stream>>>(h0, tags, hbuf);
  dim3 g1((T_STEPS * BATCH) / BM, G4 / BN);
  xi_gemm<<<g1, 256, 0, stream>>>(x, Wi, bi, bh, xi);
  lstm_rec<<<NWV, 64, 0, stream>>>(Wh, h0, xi, out, tags, hbuf);
}